// Round 14
// baseline (188.753 us; speedup 1.0000x reference)
//
#include <hip/hip_runtime.h>
#include <hip/hip_bf16.h>
#include <math.h>

#define N_ATOMS 8192
#define B_BATCH 64
#define E_EDGES 262144
#define S_SPEC 4
#define NMAX 8
#define PS_DIM 4096
#define PS_K 2304            // folded upper-tri K: 528 pairs*4 lb = 2112, pad to 9*256
#define H1_DIM 1024
#define CAP4 48
#define CUTR 5.0f
#define PI_F 3.14159265358979f

typedef float floatx4 __attribute__((ext_vector_type(4)));
typedef int intx8 __attribute__((ext_vector_type(8)));
typedef unsigned char u8;

// async global->LDS, 16B per lane; LDS dest = wave-uniform base + lane*16
__device__ __forceinline__ void g2lds16(const void* g, void* l) {
    __builtin_amdgcn_global_load_lds(
        (const __attribute__((address_space(1))) void*)g,
        (__attribute__((address_space(3))) void*)l, 16, 0, 0);
}

__device__ __forceinline__ int pk_fp8x4(float a, float b, float c, float d) {
    int lo = __builtin_amdgcn_cvt_pk_fp8_f32(a, b, 0, false);
    return __builtin_amdgcn_cvt_pk_fp8_f32(c, d, lo, true);
}

// ------------------------------------------------- merged prep (1 dispatch):
// blocks [0,512): edge scatter, 2 edges/thread ILP (block 0 zeroes out[])
// blocks [512,3840): W1 gamma-fold / W2 transpose
// block 3840: gw = gamma*Wps array + S2/S3 scalar reduction
__global__ __launch_bounds__(256) void prep_kernel(
    const float* __restrict__ pos, const float* __restrict__ cells,
    const int* __restrict__ numbers, const int* __restrict__ ei,
    const float* __restrict__ eo, const int* __restrict__ batch,
    int* __restrict__ cnt, float4* __restrict__ bucket,
    const float* __restrict__ W1, const float* __restrict__ gamma,
    const float* __restrict__ beta, const float* __restrict__ Wps,
    const float* __restrict__ W2,
    u8* __restrict__ Wt1, u8* __restrict__ Wt2, float* __restrict__ b1,
    float* __restrict__ gw, float* __restrict__ S23, float* __restrict__ out)
{
    if (blockIdx.x < 512) {
        // ---------------- scatter: 2 edges/thread, loads issued upfront ----
        if (blockIdx.x == 0 && threadIdx.x < B_BATCH) out[threadIdx.x] = 0.0f;
        int e0 = blockIdx.x * 512 + threadIdx.x;
        int e1 = e0 + 256;
        // independent gather chains for both edges (MLP)
        int i0 = ei[e0],            i1 = ei[e1];
        int j0 = ei[E_EDGES + e0],  j1 = ei[E_EDGES + e1];
        int bb0 = batch[i0],        bb1 = batch[i1];
        int sp0 = numbers[j0],      sp1 = numbers[j1];
        float o00 = eo[e0 * 3 + 0], o01 = eo[e0 * 3 + 1], o02 = eo[e0 * 3 + 2];
        float o10 = eo[e1 * 3 + 0], o11 = eo[e1 * 3 + 1], o12 = eo[e1 * 3 + 2];
        const float* c0 = cells + bb0 * 9;
        const float* c1 = cells + bb1 * 9;
        float rv0[3], rv1[3];
        #pragma unroll
        for (int d = 0; d < 3; ++d) {
            float sh0 = o00 * c0[0 * 3 + d] + o01 * c0[1 * 3 + d] + o02 * c0[2 * 3 + d];
            float sh1 = o10 * c1[0 * 3 + d] + o11 * c1[1 * 3 + d] + o12 * c1[2 * 3 + d];
            rv0[d] = pos[j0 * 3 + d] - pos[i0 * 3 + d] + sh0;
            rv1[d] = pos[j1 * 3 + d] - pos[i1 * 3 + d] + sh1;
        }
        float r20 = rv0[0] * rv0[0] + rv0[1] * rv0[1] + rv0[2] * rv0[2] + 1e-12f;
        float r21 = rv1[0] * rv1[0] + rv1[1] * rv1[1] + rv1[2] * rv1[2] + 1e-12f;
        if (r20 < CUTR * CUTR) {
            float a1 = sqrtf(r20) * (PI_F / CUTR);
            int q = i0 * S_SPEC + sp0;
            int slot = atomicAdd(&cnt[q], 1);
            if (slot < CAP4)
                bucket[q * CAP4 + slot] = make_float4(rv0[0], rv0[1], rv0[2], a1);
        }
        if (r21 < CUTR * CUTR) {
            float a1 = sqrtf(r21) * (PI_F / CUTR);
            int q = i1 * S_SPEC + sp1;
            int slot = atomicAdd(&cnt[q], 1);
            if (slot < CAP4)
                bucket[q * CAP4 + slot] = make_float4(rv1[0], rv1[1], rv1[2], a1);
        }
        return;
    }

    if (blockIdx.x == 3840) {
        // ---------------- gw + S2/S3 ----------------
        __shared__ float rs[8][2];
        int t = threadIdx.x, lane = t & 63, wv = t >> 6;
        float s2 = 0.0f, s3 = 0.0f;
        #pragma unroll
        for (int it = 0; it < 4; ++it) {
            int p4 = it * 256 + t;
            float4 g = *(const float4*)(gamma + p4 * 4);
            float4 bt = *(const float4*)(beta + p4 * 4);
            float4 w = *(const float4*)(Wps + p4 * 4);
            float4 gwv = make_float4(g.x * w.x, g.y * w.y, g.z * w.z, g.w * w.w);
            *(float4*)(gw + p4 * 4) = gwv;
            s2 += gwv.x + gwv.y + gwv.z + gwv.w;
            s3 += bt.x * w.x + bt.y * w.y + bt.z * w.z + bt.w * w.w;
        }
        #pragma unroll
        for (int o = 32; o > 0; o >>= 1) {
            s2 += __shfl_down(s2, o);
            s3 += __shfl_down(s3, o);
        }
        if (lane == 0) { rs[wv][0] = s2; rs[wv][1] = s3; }
        __syncthreads();
        if (t == 0) {
            S23[0] = rs[0][0] + rs[1][0] + rs[2][0] + rs[3][0];
            S23[1] = rs[0][1] + rs[1][1] + rs[2][1] + rs[3][1];
        }
        return;
    }

    // ---------------- weight prep ----------------
    __shared__ float tbuf[32][33];
    __shared__ float bred[8][32];
    int wid = blockIdx.x - 512;
    int by = wid & 31;          // n-tile [0,32)
    int bx = wid >> 5;          // k-tile [0,104)
    int tx = threadIdx.x & 31, ty = threadIdx.x >> 5;
    int n0 = by * 32;

    if (bx < 72) {
        int k0 = bx * 32;
        float bacc = 0.0f;
        for (int r = 0; r < 32; r += 8) {
            int kk = ty + r;
            int kp = k0 + kk;
            int u = kp >> 2, lb = kp & 3;
            float val = 0.0f;
            if (u < 528) {
                int x = 0;
                while ((x + 1) * (64 - x) / 2 <= u) ++x;
                int y = x + (u - x * (65 - x) / 2);
                int p1 = x * 128 + y * 4 + lb;
                float w1v = W1[(size_t)p1 * H1_DIM + n0 + tx];
                val = gamma[p1] * w1v;
                bacc += beta[p1] * w1v;
                if (x < y) {
                    int p2 = y * 128 + x * 4 + lb;
                    float w2v = W1[(size_t)p2 * H1_DIM + n0 + tx];
                    val += gamma[p2] * w2v;
                    bacc += beta[p2] * w2v;
                }
            }
            tbuf[kk][tx] = val;
        }
        bred[ty][tx] = bacc;
        __syncthreads();
        if (ty == 0) {
            float s = 0.0f;
            #pragma unroll
            for (int i = 0; i < 8; ++i) s += bred[i][tx];
            atomicAdd(&b1[n0 + tx], s);
        }
        if (threadIdx.x < 64) {
            int nl = threadIdx.x >> 1, cc = threadIdx.x & 1;
            int n = n0 + nl;
            unsigned int w[4];
            #pragma unroll
            for (int g = 0; g < 4; ++g) {
                int kb = cc * 16 + g * 4;
                w[g] = (unsigned int)pk_fp8x4(
                    tbuf[kb + 0][nl] * 64.0f, tbuf[kb + 1][nl] * 64.0f,
                    tbuf[kb + 2][nl] * 64.0f, tbuf[kb + 3][nl] * 64.0f);
            }
            int gc = (k0 >> 4) + cc;
            int gcs = (gc & ~7) | ((gc & 7) ^ (n & 7));
            *(uint4*)(Wt1 + (size_t)n * PS_K + (size_t)gcs * 16) =
                make_uint4(w[0], w[1], w[2], w[3]);
        }
    } else {
        int k0 = (bx - 72) * 32;
        #pragma unroll
        for (int r = 0; r < 32; r += 8)
            tbuf[ty + r][tx] = W2[(size_t)(k0 + ty + r) * H1_DIM + n0 + tx];
        __syncthreads();
        if (threadIdx.x < 64) {
            int nl = threadIdx.x >> 1, cc = threadIdx.x & 1;
            int n = n0 + nl;
            unsigned int w[4];
            #pragma unroll
            for (int g = 0; g < 4; ++g) {
                int kb = cc * 16 + g * 4;
                w[g] = (unsigned int)pk_fp8x4(
                    tbuf[kb + 0][nl] * 32.0f, tbuf[kb + 1][nl] * 32.0f,
                    tbuf[kb + 2][nl] * 32.0f, tbuf[kb + 3][nl] * 32.0f);
            }
            int gc = (k0 >> 4) + cc;
            int gcs = (gc & ~7) | ((gc & 7) ^ (n & 7));
            *(uint4*)(Wt2 + (size_t)n * H1_DIM + (size_t)gcs * 16) =
                make_uint4(w[0], w[1], w[2], w[3]);
        }
    }
}

// ---------------------------------------------------------------- fused accum + PS/LN
// R6 block structure + gw/S23 algebra (R9/R13-verified).
__global__ __launch_bounds__(256) void accum_ps_kernel(
    const float4* __restrict__ bucket, const int* __restrict__ cnt,
    const float* __restrict__ gw, const float* __restrict__ S23,
    u8* __restrict__ psn, float* __restrict__ psl)
{
    __shared__ __align__(16) float cl[4][32 * 20];   // [atom][x*20+m], ld=20
    __shared__ __align__(16) u8 ps_s8[PS_K];
    __shared__ float red[12];

    int t = threadIdx.x;
    int wv = t >> 6, lane = t & 63;
    int atom0 = blockIdx.x * 4;

    // ---------------- Phase A ----------------
    {
        int atom = atom0 + wv;
        int sp_l = lane >> 4;
        int nidx = (lane >> 1) & 7;
        float nf = (float)(nidx + 1);
        int par = lane & 1;

        int myCnt = cnt[atom * S_SPEC + sp_l];
        if (myCnt > CAP4) myCnt = CAP4;
        int m1 = max(myCnt, __shfl_xor(myCnt, 16));
        int mx = max(m1, __shfl_xor(m1, 32));

        const float4* q = bucket + (size_t)(atom * S_SPEC + sp_l) * CAP4;
        float acc[8] = {};
        #pragma unroll 2
        for (int e = 0; e < mx; ++e) {
            float4 d = q[e];
            bool valid = e < myCnt;
            float a1 = d.w;
            float inv_r = (PI_F / CUTR) * __frcp_rn(a1);
            float fc = 0.5f * __cosf(a1) + 0.5f;
            float rn = fc * inv_r * __sinf(nf * a1);
            rn = valid ? rn : 0.0f;

            float x = d.x * inv_r, y = d.y * inv_r, z = d.z * inv_r;
            float x2 = x * x, y2 = y * y, z2 = z * z;
            float Ys[8];
            if (par == 0) {
                Ys[0] = 0.28209479f;
                Ys[1] = 0.48860251f * y;
                Ys[2] = 0.48860251f * z;
                Ys[3] = 0.48860251f * x;
                Ys[4] = 1.09254843f * x * y;
                Ys[5] = 1.09254843f * y * z;
                Ys[6] = 0.31539157f * (3.0f * z2 - 1.0f);
                Ys[7] = 1.09254843f * x * z;
            } else {
                Ys[0] = 0.54627422f * (x2 - y2);
                Ys[1] = 0.59004359f * y * (3.0f * x2 - y2);
                Ys[2] = 2.89061144f * x * y * z;
                Ys[3] = 0.45704579f * y * (5.0f * z2 - 1.0f);
                Ys[4] = 0.37317633f * z * (5.0f * z2 - 3.0f);
                Ys[5] = 0.45704579f * x * (5.0f * z2 - 1.0f);
                Ys[6] = 1.44530572f * z * (x2 - y2);
                Ys[7] = 0.59004359f * x * (x2 - 3.0f * y2);
            }
            #pragma unroll
            for (int k = 0; k < 8; ++k) acc[k] += rn * Ys[k];
        }
        int X = sp_l * 8 + nidx;
        float* dst = &cl[wv][X * 20 + par * 8];
        *(float4*)(dst + 0) = make_float4(acc[0], acc[1], acc[2], acc[3]);
        *(float4*)(dst + 4) = make_float4(acc[4], acc[5], acc[6], acc[7]);
    }
    if (t < 48) ((int*)ps_s8)[528 + t] = 0;   // zero the K-pad words once
    __syncthreads();

    float S2c = S23[0], S3c = S23[1];

    // ---------------- Phase B ----------------
    for (int a = 0; a < 4; ++a) {
        int atom = atom0 + a;
        const float* cl_x = cl[a];

        int y = t & 31;
        int xb = t >> 5;
        float4 cya = *(const float4*)&cl_x[y * 20 + 0];
        float4 cyb = *(const float4*)&cl_x[y * 20 + 4];
        float4 cyc = *(const float4*)&cl_x[y * 20 + 8];
        float4 cyd = *(const float4*)&cl_x[y * 20 + 12];

        float ps[4][4];
        float sum = 0.0f, sumsq = 0.0f, S1 = 0.0f;
        #pragma unroll
        for (int q = 0; q < 4; ++q) {
            int x = xb + 8 * q;
            float4 xa = *(const float4*)&cl_x[x * 20 + 0];
            float4 xbv = *(const float4*)&cl_x[x * 20 + 4];
            float4 xc = *(const float4*)&cl_x[x * 20 + 8];
            float4 xd = *(const float4*)&cl_x[x * 20 + 12];
            float s0 = xa.x * cya.x;
            float s1 = xa.y * cya.y + xa.z * cya.z + xa.w * cya.w;
            float s2 = xbv.x * cyb.x + xbv.y * cyb.y + xbv.z * cyb.z + xbv.w * cyb.w
                     + xc.x * cyc.x;
            float s3 = xc.y * cyc.y + xc.z * cyc.z + xc.w * cyc.w
                     + xd.x * cyd.x + xd.y * cyd.y + xd.z * cyd.z + xd.w * cyd.w;
            ps[q][0] = s0; ps[q][1] = s1; ps[q][2] = s2; ps[q][3] = s3;
            sum += s0 + s1 + s2 + s3;
            sumsq += s0 * s0 + s1 * s1 + s2 * s2 + s3 * s3;
            int p = t + 256 * q;
            float4 gwv = *(const float4*)(gw + p * 4);
            S1 += s0 * gwv.x + s1 * gwv.y + s2 * gwv.z + s3 * gwv.w;
        }
        #pragma unroll
        for (int o = 32; o > 0; o >>= 1) {
            sum += __shfl_down(sum, o);
            sumsq += __shfl_down(sumsq, o);
            S1 += __shfl_down(S1, o);
        }
        if ((t & 63) == 0) { red[wv] = sum; red[4 + wv] = sumsq; red[8 + wv] = S1; }
        __syncthreads();
        float tot = red[0] + red[1] + red[2] + red[3];
        float totsq = red[4] + red[5] + red[6] + red[7];
        float S1t = red[8] + red[9] + red[10] + red[11];
        float mu = tot * (1.0f / PS_DIM);
        float var = totsq * (1.0f / PS_DIM) - mu * mu;
        float inv = rsqrtf(var + 1e-5f);
        if (t == 0) psl[atom] = inv * (S1t - mu * S2c) + S3c;

        #pragma unroll
        for (int q = 0; q < 4; ++q) {
            int p = t + 256 * q;
            float z0 = (ps[q][0] - mu) * inv;
            float z1 = (ps[q][1] - mu) * inv;
            float z2 = (ps[q][2] - mu) * inv;
            float z3 = (ps[q][3] - mu) * inv;
            int x = p >> 5, yy = p & 31;
            if (x <= yy) {
                int u = x * (65 - x) / 2 + (yy - x);
                ((int*)ps_s8)[u] = pk_fp8x4(z0, z1, z2, z3);
            }
        }
        __syncthreads();
        u8* rowp = psn + (size_t)atom * PS_K;
        if (t < PS_K / 16) {   // 144 chunks
            int gcs = (t & ~7) | ((t & 7) ^ (atom & 7));
            *(uint4*)(rowp + (size_t)gcs * 16) = *(const uint4*)(ps_s8 + (size_t)t * 16);
        }
    }
}

// ------------------------------------------------- MX-fp8 MFMA GEMM1, HIGH-OCCUPANCY
// R13 counters: MfmaUtil 16%, Occ 18.6%, HBM 7.7% -> latency-bound at 2 blocks/CU.
// Retile 64x128, BK=128: LDS = A 8KB + B 16KB = 24KB -> grid (128,8) = 1024
// blocks = 4 blocks/CU (16 waves/CU) for cross-block latency overlap. Swizzle
// is per-128B-segment so BK=128 staging keeps the verified c0/c1 read math.
// Per wave: 16 rows, 1 A-frag + 8 B-frags -> 8 MFMA per K-step; 18 K-steps.
__global__ __launch_bounds__(256) void gemm_f8_kernel(
    const u8* __restrict__ A, const u8* __restrict__ Bt,
    u8* __restrict__ H, const float* __restrict__ b1,
    int M, int Nc, int K, float invs)
{
    __shared__ __align__(16) char smem[24576];   // A: 64x128B = 8KB | B: 128x128B = 16KB
    int tid = threadIdx.x;
    int bm = blockIdx.x, bn = blockIdx.y;
    int wave = tid >> 6, lane = tid & 63;
    int wm = wave * 16;                 // wave owns rows [wm, wm+16)
    int lm = lane & 15, quad = lane >> 4;

    floatx4 acc[8] = {};
    const int rowA0 = bm * 64, rowB0 = bn * 128;   // both %8 == 0 -> key = lm&7
    const size_t stride = (size_t)K;
    const char* Ab = (const char*)A + (size_t)rowA0 * stride;
    const char* Bb = (const char*)Bt + (size_t)rowB0 * stride;
    const int sA = 0x7F7F7F7F, sB = 0x7F7F7F7F;

    int key = lm & 7;
    int c0 = (2 * quad) ^ key, c1 = (2 * quad + 1) ^ key;

    for (int k0 = 0; k0 < K; k0 += 128) {
        // stage A: 512 chunks (2 per thread), row = L>>3, chunk = L&7
        #pragma unroll
        for (int s = 0; s < 2; ++s) {
            int L = s * 256 + tid;
            int row = L >> 3, boff = (L & 7) * 16;
            int lbase = (s * 256 + wave * 64) * 16;
            g2lds16(Ab + (size_t)row * stride + k0 + boff, smem + lbase);
        }
        // stage B: 1024 chunks (4 per thread)
        #pragma unroll
        for (int s = 0; s < 4; ++s) {
            int L = s * 256 + tid;
            int row = L >> 3, boff = (L & 7) * 16;
            int lbase = (s * 256 + wave * 64) * 16;
            g2lds16(Bb + (size_t)row * stride + k0 + boff, smem + 8192 + lbase);
        }
        __syncthreads();
        intx8 af;
        {
            const char* base = smem + (wm + lm) * 128;
            uint4 lo = *(const uint4*)(base + c0 * 16);
            uint4 hi = *(const uint4*)(base + c1 * 16);
            af[0] = lo.x; af[1] = lo.y; af[2] = lo.z; af[3] = lo.w;
            af[4] = hi.x; af[5] = hi.y; af[6] = hi.z; af[7] = hi.w;
        }
        #pragma unroll
        for (int ni = 0; ni < 8; ++ni) {
            intx8 bfr;
            const char* base = smem + 8192 + (ni * 16 + lm) * 128;
            uint4 lo = *(const uint4*)(base + c0 * 16);
            uint4 hi = *(const uint4*)(base + c1 * 16);
            bfr[0] = lo.x; bfr[1] = lo.y; bfr[2] = lo.z; bfr[3] = lo.w;
            bfr[4] = hi.x; bfr[5] = hi.y; bfr[6] = hi.z; bfr[7] = hi.w;
            acc[ni] = __builtin_amdgcn_mfma_scale_f32_16x16x128_f8f6f4(
                af, bfr, acc[ni], 0, 0, 0, sA, 0, sB);
        }
        __syncthreads();
    }

    // epilogue: Cs8 = 64x128 fp8 in LDS (reuse smem; last barrier protects it)
    u8* Cs8 = (u8*)smem;
    #pragma unroll
    for (int ni = 0; ni < 8; ++ni) {
        float bv = b1[bn * 128 + ni * 16 + lm];
        #pragma unroll
        for (int r = 0; r < 4; ++r) {
            int row = wm + quad * 4 + r;
            int col = ni * 16 + lm;
            float v = acc[ni][r] * invs + bv;
            v = v / (1.0f + __expf(-v));
            int pk = __builtin_amdgcn_cvt_pk_fp8_f32(v, 0.0f, 0, false);
            Cs8[row * 128 + col] = (u8)(pk & 0xFF);
        }
    }
    __syncthreads();
    #pragma unroll
    for (int s = 0; s < 2; ++s) {
        int L = s * 256 + tid;           // 512 chunks: row = L>>3, cc = L&7
        int row = L >> 3, cc = L & 7;
        int gcs = cc ^ (row & 7);        // rowA0 % 8 == 0
        *(uint4*)(H + (size_t)(rowA0 + row) * Nc + (size_t)(bn * 8 + gcs) * 16) =
            *(const uint4*)(Cs8 + (size_t)L * 16);
    }
}

// ------------------------------------------------- GEMM2 + final reduction
__global__ __launch_bounds__(256) void gemm2_fused_kernel(
    const u8* __restrict__ A, const u8* __restrict__ Bt,
    const float* __restrict__ W3, const float* __restrict__ psl,
    const int* __restrict__ numbers, const float* __restrict__ Wcomp,
    float* __restrict__ out, int Nc, int K, float invs)
{
    __shared__ __align__(16) char smem[65536];
    int tid = threadIdx.x;
    int bm = blockIdx.x, bn = blockIdx.y;
    int wave = tid >> 6, lane = tid & 63;
    int wm = (wave >> 1) * 64, wn = (wave & 1) * 64;
    int lm = lane & 15, quad = lane >> 4;

    floatx4 acc[4][4] = {};
    const int rowA0 = bm * 128, rowB0 = bn * 128;
    const size_t stride = (size_t)K;
    const char* Ab = (const char*)A + (size_t)rowA0 * stride;
    const char* Bb = (const char*)Bt + (size_t)rowB0 * stride;
    const int sA = 0x7F7F7F7F, sB = 0x7F7F7F7F;

    for (int k0 = 0; k0 < K; k0 += 256) {
        #pragma unroll
        for (int s = 0; s < 8; ++s) {
            int L = s * 256 + tid;
            int row = L >> 4, boff = (L & 15) * 16;
            int lbase = (s * 256 + wave * 64) * 16;
            g2lds16(Ab + (size_t)row * stride + k0 + boff, smem + lbase);
        }
        #pragma unroll
        for (int s = 0; s < 8; ++s) {
            int L = s * 256 + tid;
            int row = L >> 4, boff = (L & 15) * 16;
            int lbase = (s * 256 + wave * 64) * 16;
            g2lds16(Bb + (size_t)row * stride + k0 + boff, smem + 32768 + lbase);
        }
        __syncthreads();
        int key = lm & 7;
        int c0 = (2 * quad) ^ key, c1 = (2 * quad + 1) ^ key;
        #pragma unroll
        for (int h = 0; h < 2; ++h) {
            intx8 af[4], bfr[4];
            #pragma unroll
            for (int mi = 0; mi < 4; ++mi) {
                const char* base = smem + (wm + mi * 16 + lm) * 256 + h * 128;
                uint4 lo = *(const uint4*)(base + c0 * 16);
                uint4 hi = *(const uint4*)(base + c1 * 16);
                af[mi][0] = lo.x; af[mi][1] = lo.y; af[mi][2] = lo.z; af[mi][3] = lo.w;
                af[mi][4] = hi.x; af[mi][5] = hi.y; af[mi][6] = hi.z; af[mi][7] = hi.w;
            }
            #pragma unroll
            for (int ni = 0; ni < 4; ++ni) {
                const char* base = smem + 32768 + (wn + ni * 16 + lm) * 256 + h * 128;
                uint4 lo = *(const uint4*)(base + c0 * 16);
                uint4 hi = *(const uint4*)(base + c1 * 16);
                bfr[ni][0] = lo.x; bfr[ni][1] = lo.y; bfr[ni][2] = lo.z; bfr[ni][3] = lo.w;
                bfr[ni][4] = hi.x; bfr[ni][5] = hi.y; bfr[ni][6] = hi.z; bfr[ni][7] = hi.w;
            }
            #pragma unroll
            for (int mi = 0; mi < 4; ++mi)
                #pragma unroll
                for (int ni = 0; ni < 4; ++ni)
                    acc[mi][ni] = __builtin_amdgcn_mfma_scale_f32_16x16x128_f8f6f4(
                        af[mi], bfr[ni], acc[mi][ni], 0, 0, 0, sA, 0, sB);
        }
        __syncthreads();
    }

    float lt = 0.0f;
    #pragma unroll
    for (int ni = 0; ni < 4; ++ni) {
        float w3v = W3[bn * 128 + wn + ni * 16 + lm];
        #pragma unroll
        for (int mi = 0; mi < 4; ++mi)
            #pragma unroll
            for (int r = 0; r < 4; ++r) {
                float v = acc[mi][ni][r] * invs;
                v = v / (1.0f + __expf(-v));
                lt += v * w3v;
            }
    }
    #pragma unroll
    for (int o = 32; o > 0; o >>= 1) lt += __shfl_down(lt, o);
    float* wsum = (float*)smem;          // [0..3]
    int* c4 = ((int*)smem) + 8;          // [8..11]
    float* shp = ((float*)smem) + 12;    // [12..13]
    if (tid < S_SPEC) c4[tid] = 0;
    if (lane == 0) wsum[wave] = lt;
    __syncthreads();
    if (tid == 0)
        atomicAdd(&out[bm],
                  (wsum[0] + wsum[1] + wsum[2] + wsum[3]) * (1.0f / 128.0f));
    if (bn == 0) {
        if (tid < 128) {
            int a = bm * 128 + tid;
            float e = psl[a];
            atomicAdd(&c4[numbers[a]], 1);
            #pragma unroll
            for (int o = 32; o > 0; o >>= 1) e += __shfl_down(e, o);
            if ((tid & 63) == 0) shp[tid >> 6] = e;
        }
        __syncthreads();
        if (tid == 0) {
            float r = (shp[0] + shp[1]) * (1.0f / 128.0f);
            #pragma unroll
            for (int s = 0; s < S_SPEC; ++s) r += (float)c4[s] * Wcomp[s];
            atomicAdd(&out[bm], r);
        }
    }
}

extern "C" void kernel_launch(void* const* d_in, const int* in_sizes, int n_in,
                              void* d_out, int out_size, void* d_ws, size_t ws_size,
                              hipStream_t stream)
{
    const float* positions = (const float*)d_in[0];
    const float* cells     = (const float*)d_in[1];
    const int*   numbers   = (const int*)d_in[2];
    const int*   ei        = (const int*)d_in[3];
    const float* eo        = (const float*)d_in[4];
    const int*   batch     = (const int*)d_in[5];
    const float* gamma     = (const float*)d_in[6];
    const float* beta      = (const float*)d_in[7];
    const float* W_ps      = (const float*)d_in[8];
    const float* W1        = (const float*)d_in[9];
    const float* W2        = (const float*)d_in[10];
    const float* W3        = (const float*)d_in[11];
    const float* W_comp    = (const float*)d_in[12];
    float* out = (float*)d_out;

    char* ws = (char*)d_ws;
    float4* bucket = (float4*)ws;  ws += (size_t)N_ATOMS * S_SPEC * CAP4 * 16;  // 25.2 MB
    u8*    psn  = (u8*)ws;     ws += (size_t)N_ATOMS * PS_K;               // 18.9 MB
    u8*    h1   = (u8*)ws;     ws += (size_t)N_ATOMS * H1_DIM;             // 8 MB
    u8*    Wt1  = (u8*)ws;     ws += (size_t)H1_DIM * PS_K;                // 2.4 MB
    u8*    Wt2  = (u8*)ws;     ws += (size_t)H1_DIM * H1_DIM;              // 1 MB
    float* psl  = (float*)ws;  ws += (size_t)N_ATOMS * 4;
    int*   cnt  = (int*)ws;    ws += (size_t)N_ATOMS * S_SPEC * 4;         // 128 KB
    float* b1   = (float*)ws;  ws += (size_t)H1_DIM * 4;                   // 4 KB (adjacent to cnt)
    float* gw   = (float*)ws;  ws += (size_t)PS_DIM * 4;                   // 16 KB
    float* S23  = (float*)ws;  ws += 2 * 4;

    // ONE memset covers cnt + b1 (contiguous)
    hipMemsetAsync(cnt, 0, (N_ATOMS * S_SPEC + H1_DIM) * sizeof(int), stream);

    prep_kernel<<<3841, 256, 0, stream>>>(
        positions, cells, numbers, ei, eo, batch, cnt, bucket,
        W1, gamma, beta, W_ps, W2, Wt1, Wt2, b1, gw, S23, out);

    accum_ps_kernel<<<N_ATOMS / 4, 256, 0, stream>>>(
        bucket, cnt, gw, S23, psn, psl);

    gemm_f8_kernel<<<dim3(N_ATOMS / 64, H1_DIM / 128), 256, 0, stream>>>(
        psn, Wt1, h1, b1, N_ATOMS, H1_DIM, PS_K, 1.0f / 64.0f);

    gemm2_fused_kernel<<<dim3(N_ATOMS / 128, H1_DIM / 128), 256, 0, stream>>>(
        h1, Wt2, W3, psl, numbers, W_comp, out, H1_DIM, H1_DIM, 1.0f / 32.0f);
}

// Round 15
// 181.557 us; speedup vs baseline: 1.0396x; 1.0396x over previous
//
#include <hip/hip_runtime.h>
#include <hip/hip_bf16.h>
#include <math.h>

#define N_ATOMS 8192
#define B_BATCH 64
#define E_EDGES 262144
#define S_SPEC 4
#define NMAX 8
#define PS_DIM 4096
#define PS_K 2304            // folded upper-tri K: 528 pairs*4 lb = 2112, pad to 9*256
#define H1_DIM 1024
#define CAP4 48
#define CUTR 5.0f
#define PI_F 3.14159265358979f

typedef float floatx4 __attribute__((ext_vector_type(4)));
typedef int intx8 __attribute__((ext_vector_type(8)));
typedef unsigned char u8;

// async global->LDS, 16B per lane; LDS dest = wave-uniform base + lane*16
__device__ __forceinline__ void g2lds16(const void* g, void* l) {
    __builtin_amdgcn_global_load_lds(
        (const __attribute__((address_space(1))) void*)g,
        (__attribute__((address_space(3))) void*)l, 16, 0, 0);
}

__device__ __forceinline__ int pk_fp8x4(float a, float b, float c, float d) {
    int lo = __builtin_amdgcn_cvt_pk_fp8_f32(a, b, 0, false);
    return __builtin_amdgcn_cvt_pk_fp8_f32(c, d, lo, true);
}

// ------------------------------------------------- merged prep (1 dispatch):
// blocks [0,512): edge scatter, 2 edges/thread ILP (block 0 zeroes out[])
// blocks [512,3840): W1 gamma-fold / W2 transpose
// block 3840: gw = gamma*Wps array + S2/S3 scalar reduction
__global__ __launch_bounds__(256) void prep_kernel(
    const float* __restrict__ pos, const float* __restrict__ cells,
    const int* __restrict__ numbers, const int* __restrict__ ei,
    const float* __restrict__ eo, const int* __restrict__ batch,
    int* __restrict__ cnt, float4* __restrict__ bucket,
    const float* __restrict__ W1, const float* __restrict__ gamma,
    const float* __restrict__ beta, const float* __restrict__ Wps,
    const float* __restrict__ W2,
    u8* __restrict__ Wt1, u8* __restrict__ Wt2, float* __restrict__ b1,
    float* __restrict__ gw, float* __restrict__ S23, float* __restrict__ out)
{
    if (blockIdx.x < 512) {
        // ---------------- scatter: 2 edges/thread, loads issued upfront ----
        if (blockIdx.x == 0 && threadIdx.x < B_BATCH) out[threadIdx.x] = 0.0f;
        int e0 = blockIdx.x * 512 + threadIdx.x;
        int e1 = e0 + 256;
        // independent gather chains for both edges (MLP)
        int i0 = ei[e0],            i1 = ei[e1];
        int j0 = ei[E_EDGES + e0],  j1 = ei[E_EDGES + e1];
        int bb0 = batch[i0],        bb1 = batch[i1];
        int sp0 = numbers[j0],      sp1 = numbers[j1];
        float o00 = eo[e0 * 3 + 0], o01 = eo[e0 * 3 + 1], o02 = eo[e0 * 3 + 2];
        float o10 = eo[e1 * 3 + 0], o11 = eo[e1 * 3 + 1], o12 = eo[e1 * 3 + 2];
        const float* c0 = cells + bb0 * 9;
        const float* c1 = cells + bb1 * 9;
        float rv0[3], rv1[3];
        #pragma unroll
        for (int d = 0; d < 3; ++d) {
            float sh0 = o00 * c0[0 * 3 + d] + o01 * c0[1 * 3 + d] + o02 * c0[2 * 3 + d];
            float sh1 = o10 * c1[0 * 3 + d] + o11 * c1[1 * 3 + d] + o12 * c1[2 * 3 + d];
            rv0[d] = pos[j0 * 3 + d] - pos[i0 * 3 + d] + sh0;
            rv1[d] = pos[j1 * 3 + d] - pos[i1 * 3 + d] + sh1;
        }
        float r20 = rv0[0] * rv0[0] + rv0[1] * rv0[1] + rv0[2] * rv0[2] + 1e-12f;
        float r21 = rv1[0] * rv1[0] + rv1[1] * rv1[1] + rv1[2] * rv1[2] + 1e-12f;
        if (r20 < CUTR * CUTR) {
            float a1 = sqrtf(r20) * (PI_F / CUTR);
            int q = i0 * S_SPEC + sp0;
            int slot = atomicAdd(&cnt[q], 1);
            if (slot < CAP4)
                bucket[q * CAP4 + slot] = make_float4(rv0[0], rv0[1], rv0[2], a1);
        }
        if (r21 < CUTR * CUTR) {
            float a1 = sqrtf(r21) * (PI_F / CUTR);
            int q = i1 * S_SPEC + sp1;
            int slot = atomicAdd(&cnt[q], 1);
            if (slot < CAP4)
                bucket[q * CAP4 + slot] = make_float4(rv1[0], rv1[1], rv1[2], a1);
        }
        return;
    }

    if (blockIdx.x == 3840) {
        // ---------------- gw + S2/S3 ----------------
        __shared__ float rs[8][2];
        int t = threadIdx.x, lane = t & 63, wv = t >> 6;
        float s2 = 0.0f, s3 = 0.0f;
        #pragma unroll
        for (int it = 0; it < 4; ++it) {
            int p4 = it * 256 + t;
            float4 g = *(const float4*)(gamma + p4 * 4);
            float4 bt = *(const float4*)(beta + p4 * 4);
            float4 w = *(const float4*)(Wps + p4 * 4);
            float4 gwv = make_float4(g.x * w.x, g.y * w.y, g.z * w.z, g.w * w.w);
            *(float4*)(gw + p4 * 4) = gwv;
            s2 += gwv.x + gwv.y + gwv.z + gwv.w;
            s3 += bt.x * w.x + bt.y * w.y + bt.z * w.z + bt.w * w.w;
        }
        #pragma unroll
        for (int o = 32; o > 0; o >>= 1) {
            s2 += __shfl_down(s2, o);
            s3 += __shfl_down(s3, o);
        }
        if (lane == 0) { rs[wv][0] = s2; rs[wv][1] = s3; }
        __syncthreads();
        if (t == 0) {
            S23[0] = rs[0][0] + rs[1][0] + rs[2][0] + rs[3][0];
            S23[1] = rs[0][1] + rs[1][1] + rs[2][1] + rs[3][1];
        }
        return;
    }

    // ---------------- weight prep ----------------
    __shared__ float tbuf[32][33];
    __shared__ float bred[8][32];
    int wid = blockIdx.x - 512;
    int by = wid & 31;          // n-tile [0,32)
    int bx = wid >> 5;          // k-tile [0,104)
    int tx = threadIdx.x & 31, ty = threadIdx.x >> 5;
    int n0 = by * 32;

    if (bx < 72) {
        int k0 = bx * 32;
        float bacc = 0.0f;
        for (int r = 0; r < 32; r += 8) {
            int kk = ty + r;
            int kp = k0 + kk;
            int u = kp >> 2, lb = kp & 3;
            float val = 0.0f;
            if (u < 528) {
                int x = 0;
                while ((x + 1) * (64 - x) / 2 <= u) ++x;
                int y = x + (u - x * (65 - x) / 2);
                int p1 = x * 128 + y * 4 + lb;
                float w1v = W1[(size_t)p1 * H1_DIM + n0 + tx];
                val = gamma[p1] * w1v;
                bacc += beta[p1] * w1v;
                if (x < y) {
                    int p2 = y * 128 + x * 4 + lb;
                    float w2v = W1[(size_t)p2 * H1_DIM + n0 + tx];
                    val += gamma[p2] * w2v;
                    bacc += beta[p2] * w2v;
                }
            }
            tbuf[kk][tx] = val;
        }
        bred[ty][tx] = bacc;
        __syncthreads();
        if (ty == 0) {
            float s = 0.0f;
            #pragma unroll
            for (int i = 0; i < 8; ++i) s += bred[i][tx];
            atomicAdd(&b1[n0 + tx], s);
        }
        if (threadIdx.x < 64) {
            int nl = threadIdx.x >> 1, cc = threadIdx.x & 1;
            int n = n0 + nl;
            unsigned int w[4];
            #pragma unroll
            for (int g = 0; g < 4; ++g) {
                int kb = cc * 16 + g * 4;
                w[g] = (unsigned int)pk_fp8x4(
                    tbuf[kb + 0][nl] * 64.0f, tbuf[kb + 1][nl] * 64.0f,
                    tbuf[kb + 2][nl] * 64.0f, tbuf[kb + 3][nl] * 64.0f);
            }
            int gc = (k0 >> 4) + cc;
            int gcs = (gc & ~7) | ((gc & 7) ^ (n & 7));
            *(uint4*)(Wt1 + (size_t)n * PS_K + (size_t)gcs * 16) =
                make_uint4(w[0], w[1], w[2], w[3]);
        }
    } else {
        int k0 = (bx - 72) * 32;
        #pragma unroll
        for (int r = 0; r < 32; r += 8)
            tbuf[ty + r][tx] = W2[(size_t)(k0 + ty + r) * H1_DIM + n0 + tx];
        __syncthreads();
        if (threadIdx.x < 64) {
            int nl = threadIdx.x >> 1, cc = threadIdx.x & 1;
            int n = n0 + nl;
            unsigned int w[4];
            #pragma unroll
            for (int g = 0; g < 4; ++g) {
                int kb = cc * 16 + g * 4;
                w[g] = (unsigned int)pk_fp8x4(
                    tbuf[kb + 0][nl] * 32.0f, tbuf[kb + 1][nl] * 32.0f,
                    tbuf[kb + 2][nl] * 32.0f, tbuf[kb + 3][nl] * 32.0f);
            }
            int gc = (k0 >> 4) + cc;
            int gcs = (gc & ~7) | ((gc & 7) ^ (n & 7));
            *(uint4*)(Wt2 + (size_t)n * H1_DIM + (size_t)gcs * 16) =
                make_uint4(w[0], w[1], w[2], w[3]);
        }
    }
}

// ---------------------------------------------------------------- fused accum + PS/LN
// R6 block structure + gw/S23 algebra (R9/R13-verified).
__global__ __launch_bounds__(256) void accum_ps_kernel(
    const float4* __restrict__ bucket, const int* __restrict__ cnt,
    const float* __restrict__ gw, const float* __restrict__ S23,
    u8* __restrict__ psn, float* __restrict__ psl)
{
    __shared__ __align__(16) float cl[4][32 * 20];   // [atom][x*20+m], ld=20
    __shared__ __align__(16) u8 ps_s8[PS_K];
    __shared__ float red[12];

    int t = threadIdx.x;
    int wv = t >> 6, lane = t & 63;
    int atom0 = blockIdx.x * 4;

    // ---------------- Phase A ----------------
    {
        int atom = atom0 + wv;
        int sp_l = lane >> 4;
        int nidx = (lane >> 1) & 7;
        float nf = (float)(nidx + 1);
        int par = lane & 1;

        int myCnt = cnt[atom * S_SPEC + sp_l];
        if (myCnt > CAP4) myCnt = CAP4;
        int m1 = max(myCnt, __shfl_xor(myCnt, 16));
        int mx = max(m1, __shfl_xor(m1, 32));

        const float4* q = bucket + (size_t)(atom * S_SPEC + sp_l) * CAP4;
        float acc[8] = {};
        #pragma unroll 2
        for (int e = 0; e < mx; ++e) {
            float4 d = q[e];
            bool valid = e < myCnt;
            float a1 = d.w;
            float inv_r = (PI_F / CUTR) * __frcp_rn(a1);
            float fc = 0.5f * __cosf(a1) + 0.5f;
            float rn = fc * inv_r * __sinf(nf * a1);
            rn = valid ? rn : 0.0f;

            float x = d.x * inv_r, y = d.y * inv_r, z = d.z * inv_r;
            float x2 = x * x, y2 = y * y, z2 = z * z;
            float Ys[8];
            if (par == 0) {
                Ys[0] = 0.28209479f;
                Ys[1] = 0.48860251f * y;
                Ys[2] = 0.48860251f * z;
                Ys[3] = 0.48860251f * x;
                Ys[4] = 1.09254843f * x * y;
                Ys[5] = 1.09254843f * y * z;
                Ys[6] = 0.31539157f * (3.0f * z2 - 1.0f);
                Ys[7] = 1.09254843f * x * z;
            } else {
                Ys[0] = 0.54627422f * (x2 - y2);
                Ys[1] = 0.59004359f * y * (3.0f * x2 - y2);
                Ys[2] = 2.89061144f * x * y * z;
                Ys[3] = 0.45704579f * y * (5.0f * z2 - 1.0f);
                Ys[4] = 0.37317633f * z * (5.0f * z2 - 3.0f);
                Ys[5] = 0.45704579f * x * (5.0f * z2 - 1.0f);
                Ys[6] = 1.44530572f * z * (x2 - y2);
                Ys[7] = 0.59004359f * x * (x2 - 3.0f * y2);
            }
            #pragma unroll
            for (int k = 0; k < 8; ++k) acc[k] += rn * Ys[k];
        }
        int X = sp_l * 8 + nidx;
        float* dst = &cl[wv][X * 20 + par * 8];
        *(float4*)(dst + 0) = make_float4(acc[0], acc[1], acc[2], acc[3]);
        *(float4*)(dst + 4) = make_float4(acc[4], acc[5], acc[6], acc[7]);
    }
    if (t < 48) ((int*)ps_s8)[528 + t] = 0;   // zero the K-pad words once
    __syncthreads();

    float S2c = S23[0], S3c = S23[1];

    // ---------------- Phase B ----------------
    for (int a = 0; a < 4; ++a) {
        int atom = atom0 + a;
        const float* cl_x = cl[a];

        int y = t & 31;
        int xb = t >> 5;
        float4 cya = *(const float4*)&cl_x[y * 20 + 0];
        float4 cyb = *(const float4*)&cl_x[y * 20 + 4];
        float4 cyc = *(const float4*)&cl_x[y * 20 + 8];
        float4 cyd = *(const float4*)&cl_x[y * 20 + 12];

        float ps[4][4];
        float sum = 0.0f, sumsq = 0.0f, S1 = 0.0f;
        #pragma unroll
        for (int q = 0; q < 4; ++q) {
            int x = xb + 8 * q;
            float4 xa = *(const float4*)&cl_x[x * 20 + 0];
            float4 xbv = *(const float4*)&cl_x[x * 20 + 4];
            float4 xc = *(const float4*)&cl_x[x * 20 + 8];
            float4 xd = *(const float4*)&cl_x[x * 20 + 12];
            float s0 = xa.x * cya.x;
            float s1 = xa.y * cya.y + xa.z * cya.z + xa.w * cya.w;
            float s2 = xbv.x * cyb.x + xbv.y * cyb.y + xbv.z * cyb.z + xbv.w * cyb.w
                     + xc.x * cyc.x;
            float s3 = xc.y * cyc.y + xc.z * cyc.z + xc.w * cyc.w
                     + xd.x * cyd.x + xd.y * cyd.y + xd.z * cyd.z + xd.w * cyd.w;
            ps[q][0] = s0; ps[q][1] = s1; ps[q][2] = s2; ps[q][3] = s3;
            sum += s0 + s1 + s2 + s3;
            sumsq += s0 * s0 + s1 * s1 + s2 * s2 + s3 * s3;
            int p = t + 256 * q;
            float4 gwv = *(const float4*)(gw + p * 4);
            S1 += s0 * gwv.x + s1 * gwv.y + s2 * gwv.z + s3 * gwv.w;
        }
        #pragma unroll
        for (int o = 32; o > 0; o >>= 1) {
            sum += __shfl_down(sum, o);
            sumsq += __shfl_down(sumsq, o);
            S1 += __shfl_down(S1, o);
        }
        if ((t & 63) == 0) { red[wv] = sum; red[4 + wv] = sumsq; red[8 + wv] = S1; }
        __syncthreads();
        float tot = red[0] + red[1] + red[2] + red[3];
        float totsq = red[4] + red[5] + red[6] + red[7];
        float S1t = red[8] + red[9] + red[10] + red[11];
        float mu = tot * (1.0f / PS_DIM);
        float var = totsq * (1.0f / PS_DIM) - mu * mu;
        float inv = rsqrtf(var + 1e-5f);
        if (t == 0) psl[atom] = inv * (S1t - mu * S2c) + S3c;

        #pragma unroll
        for (int q = 0; q < 4; ++q) {
            int p = t + 256 * q;
            float z0 = (ps[q][0] - mu) * inv;
            float z1 = (ps[q][1] - mu) * inv;
            float z2 = (ps[q][2] - mu) * inv;
            float z3 = (ps[q][3] - mu) * inv;
            int x = p >> 5, yy = p & 31;
            if (x <= yy) {
                int u = x * (65 - x) / 2 + (yy - x);
                ((int*)ps_s8)[u] = pk_fp8x4(z0, z1, z2, z3);
            }
        }
        __syncthreads();
        u8* rowp = psn + (size_t)atom * PS_K;
        if (t < PS_K / 16) {   // 144 chunks
            int gcs = (t & ~7) | ((t & 7) ^ (atom & 7));
            *(uint4*)(rowp + (size_t)gcs * 16) = *(const uint4*)(ps_s8 + (size_t)t * 16);
        }
    }
}

// ------------------------------------------------- MX-fp8 MFMA GEMM1 (R1 structure)
// h1 = fp8(silu(invs*zhat@W1f^T + b1)). K = PS_K = 2304 (9 BK=256 steps).
__global__ __launch_bounds__(256) void gemm_f8_kernel(
    const u8* __restrict__ A, const u8* __restrict__ Bt,
    u8* __restrict__ H, const float* __restrict__ b1,
    int M, int Nc, int K, float invs)
{
    __shared__ __align__(16) char smem[65536];   // A: 128x256B = 32KB | B: 128x256B = 32KB
    int tid = threadIdx.x;
    int bm = blockIdx.x, bn = blockIdx.y;
    int wave = tid >> 6, lane = tid & 63;
    int wm = (wave >> 1) * 64, wn = (wave & 1) * 64;
    int lm = lane & 15, quad = lane >> 4;

    floatx4 acc[4][4] = {};
    const int rowA0 = bm * 128, rowB0 = bn * 128;
    const size_t stride = (size_t)K;
    const char* Ab = (const char*)A + (size_t)rowA0 * stride;
    const char* Bb = (const char*)Bt + (size_t)rowB0 * stride;
    const int sA = 0x7F7F7F7F, sB = 0x7F7F7F7F;

    for (int k0 = 0; k0 < K; k0 += 256) {
        #pragma unroll
        for (int s = 0; s < 8; ++s) {      // A: 2048 chunks (16 per 256B row)
            int L = s * 256 + tid;
            int row = L >> 4, boff = (L & 15) * 16;
            int lbase = (s * 256 + wave * 64) * 16;
            g2lds16(Ab + (size_t)row * stride + k0 + boff, smem + lbase);
        }
        #pragma unroll
        for (int s = 0; s < 8; ++s) {      // B: 2048 chunks
            int L = s * 256 + tid;
            int row = L >> 4, boff = (L & 15) * 16;
            int lbase = (s * 256 + wave * 64) * 16;
            g2lds16(Bb + (size_t)row * stride + k0 + boff, smem + 32768 + lbase);
        }
        __syncthreads();
        int key = lm & 7;
        int c0 = (2 * quad) ^ key, c1 = (2 * quad + 1) ^ key;
        #pragma unroll
        for (int h = 0; h < 2; ++h) {      // two 128B k-subsegments per barrier
            intx8 af[4], bfr[4];
            #pragma unroll
            for (int mi = 0; mi < 4; ++mi) {
                const char* base = smem + (wm + mi * 16 + lm) * 256 + h * 128;
                uint4 lo = *(const uint4*)(base + c0 * 16);
                uint4 hi = *(const uint4*)(base + c1 * 16);
                af[mi][0] = lo.x; af[mi][1] = lo.y; af[mi][2] = lo.z; af[mi][3] = lo.w;
                af[mi][4] = hi.x; af[mi][5] = hi.y; af[mi][6] = hi.z; af[mi][7] = hi.w;
            }
            #pragma unroll
            for (int ni = 0; ni < 4; ++ni) {
                const char* base = smem + 32768 + (wn + ni * 16 + lm) * 256 + h * 128;
                uint4 lo = *(const uint4*)(base + c0 * 16);
                uint4 hi = *(const uint4*)(base + c1 * 16);
                bfr[ni][0] = lo.x; bfr[ni][1] = lo.y; bfr[ni][2] = lo.z; bfr[ni][3] = lo.w;
                bfr[ni][4] = hi.x; bfr[ni][5] = hi.y; bfr[ni][6] = hi.z; bfr[ni][7] = hi.w;
            }
            #pragma unroll
            for (int mi = 0; mi < 4; ++mi)
                #pragma unroll
                for (int ni = 0; ni < 4; ++ni)
                    acc[mi][ni] = __builtin_amdgcn_mfma_scale_f32_16x16x128_f8f6f4(
                        af[mi], bfr[ni], acc[mi][ni], 0, 0, 0, sA, 0, sB);
        }
        __syncthreads();
    }

    u8* Cs8 = (u8*)smem;                 // 128 x 128 fp8 = 16KB
    #pragma unroll
    for (int mi = 0; mi < 4; ++mi)
        #pragma unroll
        for (int ni = 0; ni < 4; ++ni) {
            float bv = b1[bn * 128 + wn + ni * 16 + lm];
            #pragma unroll
            for (int r = 0; r < 4; ++r) {
                int row = wm + mi * 16 + quad * 4 + r;
                int col = wn + ni * 16 + lm;
                float v = acc[mi][ni][r] * invs + bv;
                v = v / (1.0f + __expf(-v));
                int pk = __builtin_amdgcn_cvt_pk_fp8_f32(v, 0.0f, 0, false);
                Cs8[row * 128 + col] = (u8)(pk & 0xFF);
            }
        }
    __syncthreads();
    #pragma unroll
    for (int c2 = 0; c2 < 4; ++c2) {
        int L = c2 * 256 + tid;          // 1024 chunks: row = L>>3, cc = L&7
        int row = L >> 3, cc = L & 7;
        int gcs = cc ^ (row & 7);        // rowA0 % 8 == 0
        *(uint4*)(H + (size_t)(rowA0 + row) * Nc + (size_t)(bn * 8 + gcs) * 16) =
            *(const uint4*)(Cs8 + (size_t)L * 16);
    }
}

// ------------------------------------------------- GEMM2 + final reduction
__global__ __launch_bounds__(256) void gemm2_fused_kernel(
    const u8* __restrict__ A, const u8* __restrict__ Bt,
    const float* __restrict__ W3, const float* __restrict__ psl,
    const int* __restrict__ numbers, const float* __restrict__ Wcomp,
    float* __restrict__ out, int Nc, int K, float invs)
{
    __shared__ __align__(16) char smem[65536];
    int tid = threadIdx.x;
    int bm = blockIdx.x, bn = blockIdx.y;
    int wave = tid >> 6, lane = tid & 63;
    int wm = (wave >> 1) * 64, wn = (wave & 1) * 64;
    int lm = lane & 15, quad = lane >> 4;

    floatx4 acc[4][4] = {};
    const int rowA0 = bm * 128, rowB0 = bn * 128;
    const size_t stride = (size_t)K;
    const char* Ab = (const char*)A + (size_t)rowA0 * stride;
    const char* Bb = (const char*)Bt + (size_t)rowB0 * stride;
    const int sA = 0x7F7F7F7F, sB = 0x7F7F7F7F;

    for (int k0 = 0; k0 < K; k0 += 256) {
        #pragma unroll
        for (int s = 0; s < 8; ++s) {
            int L = s * 256 + tid;
            int row = L >> 4, boff = (L & 15) * 16;
            int lbase = (s * 256 + wave * 64) * 16;
            g2lds16(Ab + (size_t)row * stride + k0 + boff, smem + lbase);
        }
        #pragma unroll
        for (int s = 0; s < 8; ++s) {
            int L = s * 256 + tid;
            int row = L >> 4, boff = (L & 15) * 16;
            int lbase = (s * 256 + wave * 64) * 16;
            g2lds16(Bb + (size_t)row * stride + k0 + boff, smem + 32768 + lbase);
        }
        __syncthreads();
        int key = lm & 7;
        int c0 = (2 * quad) ^ key, c1 = (2 * quad + 1) ^ key;
        #pragma unroll
        for (int h = 0; h < 2; ++h) {
            intx8 af[4], bfr[4];
            #pragma unroll
            for (int mi = 0; mi < 4; ++mi) {
                const char* base = smem + (wm + mi * 16 + lm) * 256 + h * 128;
                uint4 lo = *(const uint4*)(base + c0 * 16);
                uint4 hi = *(const uint4*)(base + c1 * 16);
                af[mi][0] = lo.x; af[mi][1] = lo.y; af[mi][2] = lo.z; af[mi][3] = lo.w;
                af[mi][4] = hi.x; af[mi][5] = hi.y; af[mi][6] = hi.z; af[mi][7] = hi.w;
            }
            #pragma unroll
            for (int ni = 0; ni < 4; ++ni) {
                const char* base = smem + 32768 + (wn + ni * 16 + lm) * 256 + h * 128;
                uint4 lo = *(const uint4*)(base + c0 * 16);
                uint4 hi = *(const uint4*)(base + c1 * 16);
                bfr[ni][0] = lo.x; bfr[ni][1] = lo.y; bfr[ni][2] = lo.z; bfr[ni][3] = lo.w;
                bfr[ni][4] = hi.x; bfr[ni][5] = hi.y; bfr[ni][6] = hi.z; bfr[ni][7] = hi.w;
            }
            #pragma unroll
            for (int mi = 0; mi < 4; ++mi)
                #pragma unroll
                for (int ni = 0; ni < 4; ++ni)
                    acc[mi][ni] = __builtin_amdgcn_mfma_scale_f32_16x16x128_f8f6f4(
                        af[mi], bfr[ni], acc[mi][ni], 0, 0, 0, sA, 0, sB);
        }
        __syncthreads();
    }

    float lt = 0.0f;
    #pragma unroll
    for (int ni = 0; ni < 4; ++ni) {
        float w3v = W3[bn * 128 + wn + ni * 16 + lm];
        #pragma unroll
        for (int mi = 0; mi < 4; ++mi)
            #pragma unroll
            for (int r = 0; r < 4; ++r) {
                float v = acc[mi][ni][r] * invs;
                v = v / (1.0f + __expf(-v));
                lt += v * w3v;
            }
    }
    #pragma unroll
    for (int o = 32; o > 0; o >>= 1) lt += __shfl_down(lt, o);
    float* wsum = (float*)smem;          // [0..3]
    int* c4 = ((int*)smem) + 8;          // [8..11]
    float* shp = ((float*)smem) + 12;    // [12..13]
    if (tid < S_SPEC) c4[tid] = 0;
    if (lane == 0) wsum[wave] = lt;
    __syncthreads();
    if (tid == 0)
        atomicAdd(&out[bm],
                  (wsum[0] + wsum[1] + wsum[2] + wsum[3]) * (1.0f / 128.0f));
    if (bn == 0) {
        if (tid < 128) {
            int a = bm * 128 + tid;
            float e = psl[a];
            atomicAdd(&c4[numbers[a]], 1);
            #pragma unroll
            for (int o = 32; o > 0; o >>= 1) e += __shfl_down(e, o);
            if ((tid & 63) == 0) shp[tid >> 6] = e;
        }
        __syncthreads();
        if (tid == 0) {
            float r = (shp[0] + shp[1]) * (1.0f / 128.0f);
            #pragma unroll
            for (int s = 0; s < S_SPEC; ++s) r += (float)c4[s] * Wcomp[s];
            atomicAdd(&out[bm], r);
        }
    }
}

extern "C" void kernel_launch(void* const* d_in, const int* in_sizes, int n_in,
                              void* d_out, int out_size, void* d_ws, size_t ws_size,
                              hipStream_t stream)
{
    const float* positions = (const float*)d_in[0];
    const float* cells     = (const float*)d_in[1];
    const int*   numbers   = (const int*)d_in[2];
    const int*   ei        = (const int*)d_in[3];
    const float* eo        = (const float*)d_in[4];
    const int*   batch     = (const int*)d_in[5];
    const float* gamma     = (const float*)d_in[6];
    const float* beta      = (const float*)d_in[7];
    const float* W_ps      = (const float*)d_in[8];
    const float* W1        = (const float*)d_in[9];
    const float* W2        = (const float*)d_in[10];
    const float* W3        = (const float*)d_in[11];
    const float* W_comp    = (const float*)d_in[12];
    float* out = (float*)d_out;

    char* ws = (char*)d_ws;
    float4* bucket = (float4*)ws;  ws += (size_t)N_ATOMS * S_SPEC * CAP4 * 16;  // 25.2 MB
    u8*    psn  = (u8*)ws;     ws += (size_t)N_ATOMS * PS_K;               // 18.9 MB
    u8*    h1   = (u8*)ws;     ws += (size_t)N_ATOMS * H1_DIM;             // 8 MB
    u8*    Wt1  = (u8*)ws;     ws += (size_t)H1_DIM * PS_K;                // 2.4 MB
    u8*    Wt2  = (u8*)ws;     ws += (size_t)H1_DIM * H1_DIM;              // 1 MB
    float* psl  = (float*)ws;  ws += (size_t)N_ATOMS * 4;
    int*   cnt  = (int*)ws;    ws += (size_t)N_ATOMS * S_SPEC * 4;         // 128 KB
    float* b1   = (float*)ws;  ws += (size_t)H1_DIM * 4;                   // 4 KB (adjacent to cnt)
    float* gw   = (float*)ws;  ws += (size_t)PS_DIM * 4;                   // 16 KB
    float* S23  = (float*)ws;  ws += 2 * 4;

    // ONE memset covers cnt + b1 (contiguous)
    hipMemsetAsync(cnt, 0, (N_ATOMS * S_SPEC + H1_DIM) * sizeof(int), stream);

    prep_kernel<<<3841, 256, 0, stream>>>(
        positions, cells, numbers, ei, eo, batch, cnt, bucket,
        W1, gamma, beta, W_ps, W2, Wt1, Wt2, b1, gw, S23, out);

    accum_ps_kernel<<<N_ATOMS / 4, 256, 0, stream>>>(
        bucket, cnt, gw, S23, psn, psl);

    gemm_f8_kernel<<<dim3(N_ATOMS / 128, H1_DIM / 128), 256, 0, stream>>>(
        psn, Wt1, h1, b1, N_ATOMS, H1_DIM, PS_K, 1.0f / 64.0f);

    gemm2_fused_kernel<<<dim3(N_ATOMS / 128, H1_DIM / 128), 256, 0, stream>>>(
        h1, Wt2, W3, psl, numbers, W_comp, out, H1_DIM, H1_DIM, 1.0f / 32.0f);
}